// Round 6
// baseline (288.974 us; speedup 1.0000x reference)
//
#include <hip/hip_runtime.h>
#include <math.h>

// Problem sizes (fixed by reference)
#define Bq 1024
#define Nn 128
#define Mm 8192
#define Ss 256
#define McF 4096   // fixed m-chunk (2 chunks); ws use ~30.5 MB (proven-safe)

typedef _Float16 f16;
typedef _Float16 f16x8 __attribute__((ext_vector_type(8)));
typedef _Float16 f16x4 __attribute__((ext_vector_type(4)));
typedef float f32x4 __attribute__((ext_vector_type(4)));

#define PI_F 3.14159265358979323846f
#define INV_SQRT_PI 0.5641895835477563f
#define TINY_F 1.17549435e-38f
#define EPS_TOTAL 1e-3f
#define WSC 1024.0f   // w scaling so f16 w stays out of subnormals

// async global->LDS copy, 16B per lane; LDS dest = wave-uniform base + lane*16
#define GLOAD16(g, l) \
    __builtin_amdgcn_global_load_lds((const __attribute__((address_space(1))) void*)(g), \
                                     (__attribute__((address_space(3))) void*)(l), 16, 0, 0)

// ---------------- prep over b: |z|^2, 1/|d| ----------------
__global__ void cpsf_prep_b(const float* __restrict__ z_re, const float* __restrict__ z_im,
                            const float* __restrict__ d_re, const float* __restrict__ d_im,
                            float* __restrict__ z2, float* __restrict__ invd)
{
    const int b = blockIdx.x * 4 + (threadIdx.x >> 6);
    const int l = threadIdx.x & 63;
    const int o = b * Nn;
    float dr0 = d_re[o + l], dr1 = d_re[o + l + 64];
    float di0 = d_im[o + l], di1 = d_im[o + l + 64];
    float zr0 = z_re[o + l], zr1 = z_re[o + l + 64];
    float zi0 = z_im[o + l], zi1 = z_im[o + l + 64];
    float sd = dr0*dr0 + di0*di0 + dr1*dr1 + di1*di1;
    float sz = zr0*zr0 + zi0*zi0 + zr1*zr1 + zi1*zi1;
#pragma unroll
    for (int off = 1; off < 64; off <<= 1) {
        sd += __shfl_xor(sd, off);
        sz += __shfl_xor(sz, off);
    }
    if (l == 0) {
        float nd = sqrtf(sd);
        nd = (nd == 0.0f) ? 1.0f : nd;
        z2[b] = sz;
        invd[b] = 1.0f / nd;
    }
}

// ---------------- prep over m: folded constants (cm[8][Mm]) ----------------
// cm rows: 0=invdj 1=c1 2=c2 3=zj2 4=isp 5=isq 6=coef 7=scale
__global__ void cpsf_prep_m(const float* __restrict__ zj_re, const float* __restrict__ zj_im,
                            const float* __restrict__ dj_re, const float* __restrict__ dj_im,
                            const float* __restrict__ alpha, const float* __restrict__ sp_,
                            const float* __restrict__ sq_, float* __restrict__ cm)
{
    const int m = blockIdx.x * 4 + (threadIdx.x >> 6);
    const int l = threadIdx.x & 63;
    const int o = m * Nn;
    float dr0 = dj_re[o + l], dr1 = dj_re[o + l + 64];
    float di0 = dj_im[o + l], di1 = dj_im[o + l + 64];
    float zr0 = zj_re[o + l], zr1 = zj_re[o + l + 64];
    float zi0 = zj_im[o + l], zi1 = zj_im[o + l + 64];
    float snd = dr0*dr0 + di0*di0 + dr1*dr1 + di1*di1;
    float sc1 = dr0*zr0 + di0*zi0 + dr1*zr1 + di1*zi1;
    float sc2 = dr0*zi0 - di0*zr0 + dr1*zi1 - di1*zr1;
    float sz2 = zr0*zr0 + zi0*zi0 + zr1*zr1 + zi1*zi1;
#pragma unroll
    for (int off = 1; off < 64; off <<= 1) {
        snd += __shfl_xor(snd, off);
        sc1 += __shfl_xor(sc1, off);
        sc2 += __shfl_xor(sc2, off);
        sz2 += __shfl_xor(sz2, off);
    }
    if (l == 0) {
        float nd = sqrtf(snd);
        nd = (nd == 0.0f) ? 1.0f : nd;
        float inv = 1.0f / nd;
        cm[0*Mm + m] = inv;
        cm[1*Mm + m] = sc1 * inv;
        cm[2*Mm + m] = sc2 * inv;
        cm[3*Mm + m] = sz2;
        float sp = fmaxf(sp_[m], TINY_F);
        float sq = fmaxf(sq_[m], TINY_F);
        float sc = sqrtf(sp / PI_F);
        cm[4*Mm + m] = PI_F / sp;
        cm[5*Mm + m] = PI_F / sq;
        cm[6*Mm + m] = fmaxf(alpha[m], TINY_F) * sc * INV_SQRT_PI;
        cm[7*Mm + m] = sc;
    }
}

// ---------------- pack A-side to f16: Az=[zr|zi], Au=[ur|ui] ----------------
__global__ void cpsf_pack_ab(const float* __restrict__ z_re, const float* __restrict__ z_im,
                             const float* __restrict__ d_re, const float* __restrict__ d_im,
                             const float* __restrict__ invd, f16* __restrict__ Az, f16* __restrict__ Au)
{
    int idx = blockIdx.x * 256 + threadIdx.x;   // Bq*64 total
    int b = idx >> 6, k4 = (idx & 63) * 4;
    float4 vz, vd;
    if (k4 < 128) {
        vz = *(const float4*)(z_re + b * Nn + k4);
        vd = *(const float4*)(d_re + b * Nn + k4);
    } else {
        vz = *(const float4*)(z_im + b * Nn + k4 - 128);
        vd = *(const float4*)(d_im + b * Nn + k4 - 128);
    }
    float s = invd[b];
    *(f16x4*)(Az + b * 256 + k4) = (f16x4){(f16)vz.x, (f16)vz.y, (f16)vz.z, (f16)vz.w};
    *(f16x4*)(Au + b * 256 + k4) = (f16x4){(f16)(vd.x*s), (f16)(vd.y*s), (f16)(vd.z*s), (f16)(vd.w*s)};
}

// ---------------- pack B-side chunk: Bp[3][Mc][256] f16 ----------------
// map0=[mr|mi], map1=[-mi|mr], map2=[qr|qi]  (mr/mi = normalized dj, q = zj)
__global__ void cpsf_pack_b1(const float* __restrict__ zj_re, const float* __restrict__ zj_im,
                             const float* __restrict__ dj_re, const float* __restrict__ dj_im,
                             const float* __restrict__ cm, f16* __restrict__ Bp,
                             int Mc, int m0g, int mshift)
{
    int idx = blockIdx.x * 256 + threadIdx.x;   // 3*Mc*64 total
    int r = idx >> 6, k4 = (idx & 63) * 4;
    int p = r >> mshift, ml = r & (Mc - 1);
    int m = m0g + ml;
    float4 v; float s;
    if (p == 0) {
        v = (k4 < 128) ? *(const float4*)(dj_re + m * Nn + k4)
                       : *(const float4*)(dj_im + m * Nn + k4 - 128);
        s = cm[m];
    } else if (p == 1) {
        if (k4 < 128) { v = *(const float4*)(dj_im + m * Nn + k4); v.x=-v.x; v.y=-v.y; v.z=-v.z; v.w=-v.w; }
        else          { v = *(const float4*)(dj_re + m * Nn + k4 - 128); }
        s = cm[m];
    } else {
        v = (k4 < 128) ? *(const float4*)(zj_re + m * Nn + k4)
                       : *(const float4*)(zj_im + m * Nn + k4 - 128);
        s = 1.0f;
    }
    *(f16x4*)(Bp + (size_t)r * 256 + k4) = (f16x4){(f16)(v.x*s), (f16)(v.y*s), (f16)(v.z*s), (f16)(v.w*s)};
}

// ---------------- pack T chunk transposed: Tt[s'=512][Mc] f16, s'=s*2+ri ----------------
__global__ void cpsf_pack_tt(const float* __restrict__ T_re, const float* __restrict__ T_im,
                             f16* __restrict__ Tt, int Mc, int m0g)
{
    __shared__ float tr[64][65], ti[64][65];
    const int mb = blockIdx.x * 64, sb = blockIdx.y * 64;
    const int tid = threadIdx.x;
    const int i0 = tid >> 6, j = tid & 63;
#pragma unroll
    for (int it = 0; it < 16; ++it) {
        int i = it * 4 + i0;
        tr[i][j] = T_re[(size_t)(m0g + mb + i) * Ss + sb + j];
        ti[i][j] = T_im[(size_t)(m0g + mb + i) * Ss + sb + j];
    }
    __syncthreads();
#pragma unroll
    for (int it = 0; it < 16; ++it) {
        int jj = it * 4 + i0;
        int sp = (sb + jj) * 2;
        Tt[(size_t)sp * Mc + mb + j]       = (f16)tr[j][jj];
        Tt[(size_t)(sp + 1) * Mc + mb + j] = (f16)ti[j][jj];
    }
}

// ---------------- MFMA kernel A1: align = |<d_j,d>|^2 -> abuf (f16) ----------------
// Block 64b x 64m, 4 waves 2x2, wave tile 32b x 32m. Acc 32 AGPR -> 4 waves/SIMD.
// LDS: Au g4 x 64 = 256 slots + Bp p2 g4 x 64 = 512 slots = 12 KB.
__global__ __launch_bounds__(256, 4) void cpsf_align(
    const f16* __restrict__ Au, const f16* __restrict__ Bp,
    f16* __restrict__ abuf, int Mc)
{
    __shared__ __align__(16) f16 sm[768 * 8];

    const int tid = threadIdx.x;
    const int wid = tid >> 6;
    const int lane = tid & 63;
    const int q = lane >> 4;
    const int li = lane & 15;
    const int mb0 = blockIdx.x * 64;
    const int bb0 = blockIdx.y * 64;
    const int wb0 = (wid >> 1) * 32;
    const int wm0 = (wid & 1) * 32;

    // staging: 12 chunks of 64 slots; chunk c = i*4 + wid; slot = c*64 + lane
    const f16* gp[3];
    f16* lb[3];
#pragma unroll
    for (int i = 0; i < 3; ++i) {
        int c = i * 4 + wid;
        const f16* src;
        if (c < 4) {                                   // Au: slot = g*64 + row
            src = Au + (size_t)(bb0 + lane) * 256 + c * 8;
        } else {                                       // Bp: slot = 256 + (g*2+p)*64 + row
            int c2 = c - 4, g = c2 >> 1, p = c2 & 1;
            src = Bp + ((size_t)p * Mc + mb0 + lane) * 256 + g * 8;
        }
        gp[i] = src;
        lb[i] = sm + (size_t)c * 64 * 8;
    }

    f32x4 acc[2][2][2];
#pragma unroll
    for (int t = 0; t < 2; ++t)
#pragma unroll
        for (int u = 0; u < 2; ++u) {
            acc[t][u][0] = (f32x4){0.f,0.f,0.f,0.f};
            acc[t][u][1] = (f32x4){0.f,0.f,0.f,0.f};
        }

    for (int ks = 0; ks < 8; ++ks) {
        __syncthreads();
#pragma unroll
        for (int i = 0; i < 3; ++i) {
            GLOAD16(gp[i], lb[i]);
            gp[i] += 32;
        }
        __syncthreads();
        f16x8 au[2], bf[2][2];
#pragma unroll
        for (int t = 0; t < 2; ++t)
            au[t] = *(const f16x8*)(sm + (size_t)(q * 64 + wb0 + t * 16 + li) * 8);
#pragma unroll
        for (int p = 0; p < 2; ++p)
#pragma unroll
            for (int u = 0; u < 2; ++u)
                bf[p][u] = *(const f16x8*)(sm + (size_t)(256 + (q * 2 + p) * 64 + wm0 + u * 16 + li) * 8);
#pragma unroll
        for (int t = 0; t < 2; ++t)
#pragma unroll
            for (int u = 0; u < 2; ++u) {
                acc[t][u][0] = __builtin_amdgcn_mfma_f32_16x16x32_f16(au[t], bf[0][u], acc[t][u][0], 0, 0, 0);
                acc[t][u][1] = __builtin_amdgcn_mfma_f32_16x16x32_f16(au[t], bf[1][u], acc[t][u][1], 0, 0, 0);
            }
    }
#pragma unroll
    for (int t = 0; t < 2; ++t)
#pragma unroll
        for (int u = 0; u < 2; ++u)
#pragma unroll
            for (int r = 0; r < 4; ++r) {
                int b = bb0 + wb0 + t * 16 + q * 4 + r;
                int m = mb0 + wm0 + u * 16 + li;
                float ar = acc[t][u][0][r], ai = acc[t][u][1][r];
                abuf[(size_t)b * Mc + m] = (f16)(ar * ar + ai * ai);
            }
}

// ---------------- MFMA kernel A2: 3 dot-maps + GH epilogue -> w ----------------
// Block 64b x 64m, 4 waves 2x2, wave tile 32b x 32m. Acc 48 AGPR -> 3 waves/SIMD.
// LDS: Az g4 x 64 = 256 slots + Bp p3 g4 x 64 = 768 slots = 16 KB.
__global__ __launch_bounds__(256, 3) void cpsf_gemm_w(
    const f16* __restrict__ Az, const f16* __restrict__ Bp,
    const float* __restrict__ cm, const float* __restrict__ z2v,
    const f16* __restrict__ abuf, f16* __restrict__ wbuf,
    float* __restrict__ den, int Mc, int m0g)
{
    __shared__ __align__(16) f16 sm[1024 * 8];

    const int tid = threadIdx.x;
    const int wid = tid >> 6;
    const int lane = tid & 63;
    const int q = lane >> 4;
    const int li = lane & 15;
    const int mb0 = blockIdx.x * 64;
    const int bb0 = blockIdx.y * 64;
    const int wb0 = (wid >> 1) * 32;
    const int wm0 = (wid & 1) * 32;

    // staging: 16 chunks of 64 slots; chunk c = i*4 + wid; slot = c*64 + lane
    const f16* gp[4];
    f16* lb[4];
#pragma unroll
    for (int i = 0; i < 4; ++i) {
        int c = i * 4 + wid;
        const f16* src;
        if (c < 4) {                                   // Az: slot = g*64 + row
            src = Az + (size_t)(bb0 + lane) * 256 + c * 8;
        } else {                                       // Bp: slot = 256 + (g*3+p)*64 + row
            int c2 = c - 4, g = c2 / 3, p = c2 % 3;
            src = Bp + ((size_t)p * Mc + mb0 + lane) * 256 + g * 8;
        }
        gp[i] = src;
        lb[i] = sm + (size_t)c * 64 * 8;
    }

    f32x4 accP[2][2][3];
#pragma unroll
    for (int t = 0; t < 2; ++t)
#pragma unroll
        for (int u = 0; u < 2; ++u)
#pragma unroll
            for (int p = 0; p < 3; ++p) accP[t][u][p] = (f32x4){0.f,0.f,0.f,0.f};

    for (int ks = 0; ks < 8; ++ks) {
        __syncthreads();
#pragma unroll
        for (int i = 0; i < 4; ++i) {
            GLOAD16(gp[i], lb[i]);
            gp[i] += 32;
        }
        __syncthreads();
        f16x8 az[2], bf[3][2];
#pragma unroll
        for (int t = 0; t < 2; ++t)
            az[t] = *(const f16x8*)(sm + (size_t)(q * 64 + wb0 + t * 16 + li) * 8);
#pragma unroll
        for (int p = 0; p < 3; ++p)
#pragma unroll
            for (int u = 0; u < 2; ++u)
                bf[p][u] = *(const f16x8*)(sm + (size_t)(256 + (q * 3 + p) * 64 + wm0 + u * 16 + li) * 8);
#pragma unroll
        for (int t = 0; t < 2; ++t)
#pragma unroll
            for (int u = 0; u < 2; ++u)
#pragma unroll
                for (int p = 0; p < 3; ++p)
                    accP[t][u][p] = __builtin_amdgcn_mfma_f32_16x16x32_f16(az[t], bf[p][u], accP[t][u][p], 0, 0, 0);
    }

    // ---------------- epilogue (fp32) ----------------
    const float GT[8] = {-2.9306374202572440f, -1.9816567566958429f,
                         -1.1571937124467802f, -0.3811869902073221f,
                          0.3811869902073221f,  1.1571937124467802f,
                          1.9816567566958429f,  2.9306374202572440f};
    const float GW[8] = {1.9960407221136762e-04f, 1.7077983007413475e-02f,
                         2.0780232581489188e-01f, 6.6114701255824129e-01f,
                         6.6114701255824129e-01f, 2.0780232581489188e-01f,
                         1.7077983007413475e-02f, 1.9960407221136762e-04f};

    // hoist all align loads (separate buffer -> no aliasing, fully pipelined)
    float alv[2][2][4];
#pragma unroll
    for (int t = 0; t < 2; ++t)
#pragma unroll
        for (int u = 0; u < 2; ++u)
#pragma unroll
            for (int r = 0; r < 4; ++r) {
                int b = bb0 + wb0 + t * 16 + q * 4 + r;
                alv[t][u][r] = (float)abuf[(size_t)b * Mc + mb0 + wm0 + u * 16 + li];
            }

    float c1[2], c2[2], zj2[2], isp[2], isq[2], cf[2], scl[2];
#pragma unroll
    for (int u = 0; u < 2; ++u) {
        int mg = m0g + mb0 + wm0 + u * 16 + li;
        c1[u]  = cm[1*Mm + mg];  c2[u]  = cm[2*Mm + mg];
        zj2[u] = cm[3*Mm + mg];  isp[u] = cm[4*Mm + mg];
        isq[u] = cm[5*Mm + mg];  cf[u]  = cm[6*Mm + mg];
        scl[u] = cm[7*Mm + mg];
    }

    float dsum[2][4];
#pragma unroll
    for (int t = 0; t < 2; ++t)
#pragma unroll
        for (int r = 0; r < 4; ++r) dsum[t][r] = 0.f;

#pragma unroll
    for (int t = 0; t < 2; ++t) {
#pragma unroll
        for (int r = 0; r < 4; ++r) {
            const int b = bb0 + wb0 + t * 16 + q * 4 + r;
            const float z2b = z2v[b];
#pragma unroll
            for (int u = 0; u < 2; ++u) {
                float pr = accP[t][u][0][r] - c1[u];
                float pi = accP[t][u][1][r] - c2[u];
                float dz2 = z2b + zj2[u] - 2.0f * accP[t][u][2][r];
                float perp2 = fmaxf(dz2 - pr * pr - pi * pi, 0.0f);
                float base = -(isq[u] * perp2 + isp[u] * pi * pi);
                float rho = 0.0f;
#pragma unroll
                for (int k = 0; k < 8; ++k) {
                    float dd = pr - scl[u] * GT[k];
                    rho = fmaf(GW[k], __expf(base - isp[u] * dd * dd), rho);
                }
                float wv = cf[u] * alv[t][u][r] * rho;
                dsum[t][r] += wv;
                wbuf[(size_t)b * Mc + mb0 + wm0 + u * 16 + li] = (f16)(wv * WSC);
            }
        }
    }
    // den: reduce across m (lane bits 0..3), atomic per b
#pragma unroll
    for (int t = 0; t < 2; ++t)
#pragma unroll
        for (int r = 0; r < 4; ++r) {
            float v = dsum[t][r];
            v += __shfl_xor(v, 1);
            v += __shfl_xor(v, 2);
            v += __shfl_xor(v, 4);
            v += __shfl_xor(v, 8);
            if (li == 0) atomicAdd(den + bb0 + wb0 + t * 16 + q * 4 + r, v);
        }
}

// ---------------- MFMA kernel B: out_acc += w @ Tt^T ----------------
// Block 64b x 128s', 4 waves 2x2, wave tile 32b x 64s'. Acc 32 AGPR -> 4 waves/SIMD.
// K-window 512 per block (z-split). LDS: w 256 + Tt 512 slots = 12 KB.
__global__ __launch_bounds__(256, 4) void cpsf_gemm_out(
    const f16* __restrict__ wbuf, const f16* __restrict__ Tt,
    float* __restrict__ oacc, int Mc)
{
    __shared__ __align__(16) f16 sm[768 * 8];
    const int tid = threadIdx.x;
    const int wid = tid >> 6;
    const int lane = tid & 63;
    const int q = lane >> 4;
    const int li = lane & 15;
    const int sb0 = blockIdx.x * 128;
    const int bb0 = blockIdx.y * 64;
    const int kz0 = blockIdx.z * 512;
    const int wb0 = (wid >> 1) * 32;
    const int ws0 = (wid & 1) * 64;

    const f16* gp[3];
    f16* lb[3];
#pragma unroll
    for (int i = 0; i < 3; ++i) {
        int c = i * 4 + wid;
        const f16* src;
        if (c < 4) {                                   // w: slot = g*64 + row
            src = wbuf + (size_t)(bb0 + lane) * Mc + kz0 + c * 8;
        } else {                                       // Tt: slot = 256 + g*128 + row
            int c2 = c - 4, g = c2 >> 1, rh = c2 & 1;
            src = Tt + (size_t)(sb0 + rh * 64 + lane) * Mc + kz0 + g * 8;
        }
        gp[i] = src;
        lb[i] = sm + (size_t)c * 64 * 8;
    }

    f32x4 acc[2][4];
#pragma unroll
    for (int t = 0; t < 2; ++t)
#pragma unroll
        for (int u = 0; u < 4; ++u) acc[t][u] = (f32x4){0.f,0.f,0.f,0.f};

    for (int kc = 0; kc < 512; kc += 32) {
        __syncthreads();
#pragma unroll
        for (int i = 0; i < 3; ++i) {
            GLOAD16(gp[i], lb[i]);
            gp[i] += 32;
        }
        __syncthreads();
        f16x8 af[2], bf[4];
#pragma unroll
        for (int t = 0; t < 2; ++t)
            af[t] = *(const f16x8*)(sm + (size_t)(q * 64 + wb0 + t * 16 + li) * 8);
#pragma unroll
        for (int u = 0; u < 4; ++u)
            bf[u] = *(const f16x8*)(sm + (size_t)(256 + q * 128 + ws0 + u * 16 + li) * 8);
#pragma unroll
        for (int t = 0; t < 2; ++t)
#pragma unroll
            for (int u = 0; u < 4; ++u)
                acc[t][u] = __builtin_amdgcn_mfma_f32_16x16x32_f16(af[t], bf[u], acc[t][u], 0, 0, 0);
    }
#pragma unroll
    for (int t = 0; t < 2; ++t)
#pragma unroll
        for (int u = 0; u < 4; ++u)
#pragma unroll
            for (int r = 0; r < 4; ++r)
                atomicAdd(oacc + (size_t)(bb0 + wb0 + t * 16 + q * 4 + r) * 512 + sb0 + ws0 + u * 16 + li,
                          acc[t][u][r]);
}

// ---------------- finalize ----------------
__global__ void cpsf_fin(const float* __restrict__ oacc, const float* __restrict__ den,
                         float* __restrict__ out)
{
    int i = blockIdx.x * 256 + threadIdx.x;
    float d = (den[i >> 9] + EPS_TOTAL) * WSC;
    out[i] = oacc[i] / d;
}

extern "C" void kernel_launch(void* const* d_in, const int* in_sizes, int n_in,
                              void* d_out, int out_size, void* d_ws, size_t ws_size,
                              hipStream_t stream)
{
    (void)in_sizes; (void)n_in; (void)out_size; (void)ws_size;
    const float* z_re  = (const float*)d_in[0];
    const float* z_im  = (const float*)d_in[1];
    const float* d_re  = (const float*)d_in[2];
    const float* d_im  = (const float*)d_in[3];
    const float* zj_re = (const float*)d_in[4];
    const float* zj_im = (const float*)d_in[5];
    const float* dj_re = (const float*)d_in[6];
    const float* dj_im = (const float*)d_in[7];
    const float* T_re  = (const float*)d_in[8];
    const float* T_im  = (const float*)d_in[9];
    const float* alpha = (const float*)d_in[10];
    const float* s_par = (const float*)d_in[11];
    const float* s_perp= (const float*)d_in[12];

    const int Mc = McF;
    const int mshift = 12;   // log2(Mc)

    // workspace layout (bytes); total ~30.5 MB
    char* w8 = (char*)d_ws;
    const size_t o_out  = 0;
    const size_t o_den  = o_out + (size_t)Bq * 512 * 4;   // 2 MB
    const size_t o_z2   = o_den + 4096;
    const size_t o_invd = o_z2 + 4096;
    const size_t o_cm   = o_invd + 4096;
    const size_t o_az   = o_cm + (size_t)8 * Mm * 4;      // 256 KB
    const size_t o_au   = o_az + (size_t)Bq * 256 * 2;
    const size_t o_ch   = o_au + (size_t)Bq * 256 * 2;
    // per-chunk: Bp 1536*Mc + Tt 1024*Mc + wbuf 2048*Mc + abuf 2048*Mc

    float* oacc = (float*)(w8 + o_out);
    float* den  = (float*)(w8 + o_den);
    float* z2   = (float*)(w8 + o_z2);
    float* invd = (float*)(w8 + o_invd);
    float* cm   = (float*)(w8 + o_cm);
    f16*   Az   = (f16*)(w8 + o_az);
    f16*   Au   = (f16*)(w8 + o_au);
    f16*   Bp   = (f16*)(w8 + o_ch);
    f16*   Tt   = (f16*)(w8 + o_ch + (size_t)1536 * Mc);
    f16*   wb   = (f16*)(w8 + o_ch + (size_t)2560 * Mc);
    f16*   ab   = (f16*)(w8 + o_ch + (size_t)4608 * Mc);

    hipMemsetAsync(d_ws, 0, o_z2, stream);   // zero out_acc + den

    cpsf_prep_b<<<Bq / 4, 256, 0, stream>>>(z_re, z_im, d_re, d_im, z2, invd);
    cpsf_prep_m<<<Mm / 4, 256, 0, stream>>>(zj_re, zj_im, dj_re, dj_im, alpha, s_par, s_perp, cm);
    cpsf_pack_ab<<<(Bq * 64) / 256, 256, 0, stream>>>(z_re, z_im, d_re, d_im, invd, Az, Au);

    for (int m0 = 0; m0 < Mm; m0 += Mc) {
        cpsf_pack_b1<<<(3 * Mc * 64) / 256, 256, 0, stream>>>(zj_re, zj_im, dj_re, dj_im,
                                                              cm, Bp, Mc, m0, mshift);
        cpsf_pack_tt<<<dim3(Mc / 64, Ss / 64), 256, 0, stream>>>(T_re, T_im, Tt, Mc, m0);
        cpsf_align<<<dim3(Mc / 64, Bq / 64), 256, 0, stream>>>(Au, Bp, ab, Mc);
        cpsf_gemm_w<<<dim3(Mc / 64, Bq / 64), 256, 0, stream>>>(Az, Bp, cm, z2, ab, wb, den, Mc, m0);
        cpsf_gemm_out<<<dim3(4, Bq / 64, Mc / 512), 256, 0, stream>>>(wb, Tt, oacc, Mc);
    }
    cpsf_fin<<<(Bq * 512) / 256, 256, 0, stream>>>(oacc, den, (float*)d_out);
}

// Round 7
// 253.913 us; speedup vs baseline: 1.1381x; 1.1381x over previous
//
#include <hip/hip_runtime.h>
#include <math.h>

// Problem sizes (fixed by reference)
#define Bq 1024
#define Nn 128
#define Mm 8192
#define Ss 256

typedef _Float16 f16;
typedef _Float16 f16x8 __attribute__((ext_vector_type(8)));
typedef float f32x4 __attribute__((ext_vector_type(4)));

#define PI_F 3.14159265358979323846f
#define INV_SQRT_PI 0.5641895835477563f
#define TINY_F 1.17549435e-38f
#define EPS_TOTAL 1e-3f
#define WSC 1024.0f   // w scaling so f16 w stays out of subnormals

// async global->LDS copy, 16B per lane; LDS dest = wave-uniform base + lane*16
#define GLOAD16(g, l) \
    __builtin_amdgcn_global_load_lds((const __attribute__((address_space(1))) void*)(g), \
                                     (__attribute__((address_space(3))) void*)(l), 16, 0, 0)

// ---------------- prep A: |z|^2, 1/|d|, pack Az=[zr|zi], Au=[ur|ui] ----------------
__global__ void cpsf_prep_a(const float* __restrict__ z_re, const float* __restrict__ z_im,
                            const float* __restrict__ d_re, const float* __restrict__ d_im,
                            float* __restrict__ z2, f16* __restrict__ Az, f16* __restrict__ Au)
{
    const int b = blockIdx.x * 4 + (threadIdx.x >> 6);
    const int l = threadIdx.x & 63;
    const int o = b * Nn;
    float dr0 = d_re[o + l], dr1 = d_re[o + l + 64];
    float di0 = d_im[o + l], di1 = d_im[o + l + 64];
    float zr0 = z_re[o + l], zr1 = z_re[o + l + 64];
    float zi0 = z_im[o + l], zi1 = z_im[o + l + 64];
    float sd = dr0*dr0 + di0*di0 + dr1*dr1 + di1*di1;
    float sz = zr0*zr0 + zi0*zi0 + zr1*zr1 + zi1*zi1;
#pragma unroll
    for (int off = 1; off < 64; off <<= 1) {
        sd += __shfl_xor(sd, off);
        sz += __shfl_xor(sz, off);
    }
    float nd = sqrtf(sd);
    nd = (nd == 0.0f) ? 1.0f : nd;
    float inv = 1.0f / nd;
    if (l == 0) z2[b] = sz;
    const int o2 = b * 256;
    Az[o2 + l]       = (f16)zr0;  Az[o2 + 64 + l]  = (f16)zr1;
    Az[o2 + 128 + l] = (f16)zi0;  Az[o2 + 192 + l] = (f16)zi1;
    Au[o2 + l]       = (f16)(dr0*inv);  Au[o2 + 64 + l]  = (f16)(dr1*inv);
    Au[o2 + 128 + l] = (f16)(di0*inv);  Au[o2 + 192 + l] = (f16)(di1*inv);
}

// ---------------- prep M: folded constants + pack Bp[3][Mm][256] ----------------
// map0=[mr|mi], map1=[-mi|mr], map2=[qr|qi]; cm rows 1..7 = c1,c2,zj2,isp,isq,coef,scale
__global__ void cpsf_prep_m(const float* __restrict__ zj_re, const float* __restrict__ zj_im,
                            const float* __restrict__ dj_re, const float* __restrict__ dj_im,
                            const float* __restrict__ alpha, const float* __restrict__ sp_,
                            const float* __restrict__ sq_, float* __restrict__ cm,
                            f16* __restrict__ Bp)
{
    const int m = blockIdx.x * 4 + (threadIdx.x >> 6);
    const int l = threadIdx.x & 63;
    const int o = m * Nn;
    float dr0 = dj_re[o + l], dr1 = dj_re[o + l + 64];
    float di0 = dj_im[o + l], di1 = dj_im[o + l + 64];
    float zr0 = zj_re[o + l], zr1 = zj_re[o + l + 64];
    float zi0 = zj_im[o + l], zi1 = zj_im[o + l + 64];
    float snd = dr0*dr0 + di0*di0 + dr1*dr1 + di1*di1;
    float sc1 = dr0*zr0 + di0*zi0 + dr1*zr1 + di1*zi1;
    float sc2 = dr0*zi0 - di0*zr0 + dr1*zi1 - di1*zr1;
    float sz2 = zr0*zr0 + zi0*zi0 + zr1*zr1 + zi1*zi1;
#pragma unroll
    for (int off = 1; off < 64; off <<= 1) {
        snd += __shfl_xor(snd, off);
        sc1 += __shfl_xor(sc1, off);
        sc2 += __shfl_xor(sc2, off);
        sz2 += __shfl_xor(sz2, off);
    }
    float nd = sqrtf(snd);
    nd = (nd == 0.0f) ? 1.0f : nd;
    float inv = 1.0f / nd;
    const size_t b0o = (size_t)m * 256;
    const size_t b1o = ((size_t)Mm + m) * 256;
    const size_t b2o = ((size_t)2 * Mm + m) * 256;
    Bp[b0o + l]       = (f16)(dr0*inv);  Bp[b0o + 64 + l]  = (f16)(dr1*inv);
    Bp[b0o + 128 + l] = (f16)(di0*inv);  Bp[b0o + 192 + l] = (f16)(di1*inv);
    Bp[b1o + l]       = (f16)(-di0*inv); Bp[b1o + 64 + l]  = (f16)(-di1*inv);
    Bp[b1o + 128 + l] = (f16)(dr0*inv);  Bp[b1o + 192 + l] = (f16)(dr1*inv);
    Bp[b2o + l]       = (f16)zr0;        Bp[b2o + 64 + l]  = (f16)zr1;
    Bp[b2o + 128 + l] = (f16)zi0;        Bp[b2o + 192 + l] = (f16)zi1;
    if (l == 0) {
        cm[1*Mm + m] = sc1 * inv;
        cm[2*Mm + m] = sc2 * inv;
        cm[3*Mm + m] = sz2;
        float sp = fmaxf(sp_[m], TINY_F);
        float sq = fmaxf(sq_[m], TINY_F);
        float sc = sqrtf(sp / PI_F);
        cm[4*Mm + m] = PI_F / sp;
        cm[5*Mm + m] = PI_F / sq;
        cm[6*Mm + m] = fmaxf(alpha[m], TINY_F) * sc * INV_SQRT_PI;
        cm[7*Mm + m] = sc;
    }
}

// ---------------- pack T transposed: Tt[s'=512][Mm] f16, s'=s*2+ri ----------------
__global__ void cpsf_pack_tt(const float* __restrict__ T_re, const float* __restrict__ T_im,
                             f16* __restrict__ Tt)
{
    __shared__ float tr[64][65], ti[64][65];
    const int mb = blockIdx.x * 64, sb = blockIdx.y * 64;
    const int tid = threadIdx.x;
    const int i0 = tid >> 6, j = tid & 63;
#pragma unroll
    for (int it = 0; it < 16; ++it) {
        int i = it * 4 + i0;
        tr[i][j] = T_re[(size_t)(mb + i) * Ss + sb + j];
        ti[i][j] = T_im[(size_t)(mb + i) * Ss + sb + j];
    }
    __syncthreads();
#pragma unroll
    for (int it = 0; it < 16; ++it) {
        int jj = it * 4 + i0;
        int sp = (sb + jj) * 2;
        Tt[(size_t)sp * Mm + mb + j]       = (f16)tr[j][jj];
        Tt[(size_t)(sp + 1) * Mm + mb + j] = (f16)ti[j][jj];
    }
}

// ---------------- MFMA kernel W: fused 5 dot-maps + GH epilogue -> w ----------------
// Block 64b x 64m, 4 waves 2x2, wave tile 32b x 32m, K=256, BK=64 (4 iters).
// Acc 80 regs (3 P-maps + 2 Q-maps x 16). LDS: Az 512 + Au 512 + Bp 1536 slots = 40 KB.
__global__ __launch_bounds__(256, 3) void cpsf_gemm_w(
    const f16* __restrict__ Az, const f16* __restrict__ Au,
    const f16* __restrict__ Bp, const float* __restrict__ cm,
    const float* __restrict__ z2v, f16* __restrict__ wbuf,
    float* __restrict__ den)
{
    __shared__ __align__(16) f16 sm[2560 * 8];

    const int tid = threadIdx.x;
    const int wid = tid >> 6;
    const int lane = tid & 63;
    const int q = lane >> 4;
    const int li = lane & 15;
    const int mb0 = blockIdx.x * 64;
    const int bb0 = blockIdx.y * 64;
    const int wb0 = (wid >> 1) * 32;
    const int wm0 = (wid & 1) * 32;

    // staging: 40 chunks of 64 slots; chunk c = i*4 + wid; slot = c*64 + lane
    const f16* gp[10];
    f16* lb[10];
#pragma unroll
    for (int i = 0; i < 10; ++i) {
        int c = i * 4 + wid;
        const f16* src;
        if (c < 8) {                                    // Az: slot = g*64 + row
            src = Az + (size_t)(bb0 + lane) * 256 + c * 8;
        } else if (c < 16) {                            // Au: slot = 512 + g*64 + row
            int g = c - 8;
            src = Au + (size_t)(bb0 + lane) * 256 + g * 8;
        } else {                                        // Bp: slot = 1024 + (g*3+p)*64 + row
            int c2 = c - 16, g = c2 / 3, p = c2 % 3;
            src = Bp + ((size_t)p * Mm + mb0 + lane) * 256 + g * 8;
        }
        gp[i] = src;
        lb[i] = sm + (size_t)c * 64 * 8;
    }

    f32x4 accP[2][2][3];   // pr_raw, pi_raw, z.zj
    f32x4 accQ[2][2][2];   // ar, ai
#pragma unroll
    for (int t = 0; t < 2; ++t)
#pragma unroll
        for (int u = 0; u < 2; ++u) {
#pragma unroll
            for (int p = 0; p < 3; ++p) accP[t][u][p] = (f32x4){0.f,0.f,0.f,0.f};
#pragma unroll
            for (int p = 0; p < 2; ++p) accQ[t][u][p] = (f32x4){0.f,0.f,0.f,0.f};
        }

    for (int ks = 0; ks < 4; ++ks) {       // BK=64
        __syncthreads();
#pragma unroll
        for (int i = 0; i < 10; ++i) {
            GLOAD16(gp[i], lb[i]);
            gp[i] += 64;
        }
        __syncthreads();
#pragma unroll
        for (int j = 0; j < 2; ++j) {      // two K=32 sub-steps
            const int g = j * 4 + q;
            f16x8 az[2], au[2], bf[3][2];
#pragma unroll
            for (int t = 0; t < 2; ++t) {
                az[t] = *(const f16x8*)(sm + (size_t)(g * 64 + wb0 + t * 16 + li) * 8);
                au[t] = *(const f16x8*)(sm + (size_t)(512 + g * 64 + wb0 + t * 16 + li) * 8);
            }
#pragma unroll
            for (int p = 0; p < 3; ++p)
#pragma unroll
                for (int u = 0; u < 2; ++u)
                    bf[p][u] = *(const f16x8*)(sm + (size_t)(1024 + (g * 3 + p) * 64 + wm0 + u * 16 + li) * 8);
#pragma unroll
            for (int t = 0; t < 2; ++t)
#pragma unroll
                for (int u = 0; u < 2; ++u) {
#pragma unroll
                    for (int p = 0; p < 3; ++p)
                        accP[t][u][p] = __builtin_amdgcn_mfma_f32_16x16x32_f16(az[t], bf[p][u], accP[t][u][p], 0, 0, 0);
                    accQ[t][u][0] = __builtin_amdgcn_mfma_f32_16x16x32_f16(au[t], bf[0][u], accQ[t][u][0], 0, 0, 0);
                    accQ[t][u][1] = __builtin_amdgcn_mfma_f32_16x16x32_f16(au[t], bf[1][u], accQ[t][u][1], 0, 0, 0);
                }
        }
    }

    // ---------------- epilogue (fp32) ----------------
    const float GT[8] = {-2.9306374202572440f, -1.9816567566958429f,
                         -1.1571937124467802f, -0.3811869902073221f,
                          0.3811869902073221f,  1.1571937124467802f,
                          1.9816567566958429f,  2.9306374202572440f};
    const float GW[8] = {1.9960407221136762e-04f, 1.7077983007413475e-02f,
                         2.0780232581489188e-01f, 6.6114701255824129e-01f,
                         6.6114701255824129e-01f, 2.0780232581489188e-01f,
                         1.7077983007413475e-02f, 1.9960407221136762e-04f};

    float c1[2], c2[2], zj2[2], isp[2], isq[2], cf[2], scl[2];
#pragma unroll
    for (int u = 0; u < 2; ++u) {
        int mg = mb0 + wm0 + u * 16 + li;
        c1[u]  = cm[1*Mm + mg];  c2[u]  = cm[2*Mm + mg];
        zj2[u] = cm[3*Mm + mg];  isp[u] = cm[4*Mm + mg];
        isq[u] = cm[5*Mm + mg];  cf[u]  = cm[6*Mm + mg];
        scl[u] = cm[7*Mm + mg];
    }

    float dsum[2][4];
#pragma unroll
    for (int t = 0; t < 2; ++t)
#pragma unroll
        for (int r = 0; r < 4; ++r) dsum[t][r] = 0.f;

#pragma unroll
    for (int t = 0; t < 2; ++t) {
#pragma unroll
        for (int r = 0; r < 4; ++r) {
            const int b = bb0 + wb0 + t * 16 + q * 4 + r;
            const float z2b = z2v[b];
#pragma unroll
            for (int u = 0; u < 2; ++u) {
                float pr = accP[t][u][0][r] - c1[u];
                float pi = accP[t][u][1][r] - c2[u];
                float dz2 = z2b + zj2[u] - 2.0f * accP[t][u][2][r];
                float perp2 = fmaxf(dz2 - pr * pr - pi * pi, 0.0f);
                float base = -(isq[u] * perp2 + isp[u] * pi * pi);
                float rho = 0.0f;
#pragma unroll
                for (int k = 0; k < 8; ++k) {
                    float dd = pr - scl[u] * GT[k];
                    rho = fmaf(GW[k], __expf(base - isp[u] * dd * dd), rho);
                }
                float ar = accQ[t][u][0][r], ai = accQ[t][u][1][r];
                float wv = cf[u] * (ar * ar + ai * ai) * rho;
                dsum[t][r] += wv;
                wbuf[(size_t)b * Mm + mb0 + wm0 + u * 16 + li] = (f16)(wv * WSC);
            }
        }
    }
    // den: reduce across m (lane bits 0..3), atomic per b
#pragma unroll
    for (int t = 0; t < 2; ++t)
#pragma unroll
        for (int r = 0; r < 4; ++r) {
            float v = dsum[t][r];
            v += __shfl_xor(v, 1);
            v += __shfl_xor(v, 2);
            v += __shfl_xor(v, 4);
            v += __shfl_xor(v, 8);
            if (li == 0) atomicAdd(den + bb0 + wb0 + t * 16 + q * 4 + r, v);
        }
}

// ---------------- MFMA kernel B: out_acc += w @ Tt^T ----------------
// Block 64b x 128s', 4 waves 2x2, wave tile 32b x 64s'. BK=64 (16 iters of K=1024).
// LDS: w 512 + Tt 1024 slots = 24 KB.
__global__ __launch_bounds__(256, 4) void cpsf_gemm_out(
    const f16* __restrict__ wbuf, const f16* __restrict__ Tt,
    float* __restrict__ oacc)
{
    __shared__ __align__(16) f16 sm[1536 * 8];
    const int tid = threadIdx.x;
    const int wid = tid >> 6;
    const int lane = tid & 63;
    const int q = lane >> 4;
    const int li = lane & 15;
    const int sb0 = blockIdx.x * 128;
    const int bb0 = blockIdx.y * 64;
    const int kz0 = blockIdx.z * 1024;
    const int wb0 = (wid >> 1) * 32;
    const int ws0 = (wid & 1) * 64;

    const f16* gp[6];
    f16* lb[6];
#pragma unroll
    for (int i = 0; i < 6; ++i) {
        int c = i * 4 + wid;
        const f16* src;
        f16* dst;
        if (c < 8) {                       // w: slot = g*64 + row
            src = wbuf + (size_t)(bb0 + lane) * Mm + kz0 + c * 8;
            dst = sm + (size_t)c * 64 * 8;
        } else {                           // Tt: slot = 512 + g*128 + rh*64 + row
            int c2 = c - 8, g = c2 >> 1, rh = c2 & 1;
            src = Tt + (size_t)(sb0 + rh * 64 + lane) * Mm + kz0 + g * 8;
            dst = sm + (size_t)(512 + g * 128 + rh * 64) * 8;
        }
        gp[i] = src;
        lb[i] = dst;
    }

    f32x4 acc[2][4];
#pragma unroll
    for (int t = 0; t < 2; ++t)
#pragma unroll
        for (int u = 0; u < 4; ++u) acc[t][u] = (f32x4){0.f,0.f,0.f,0.f};

    for (int ks = 0; ks < 16; ++ks) {      // BK=64
        __syncthreads();
#pragma unroll
        for (int i = 0; i < 6; ++i) {
            GLOAD16(gp[i], lb[i]);
            gp[i] += 64;
        }
        __syncthreads();
#pragma unroll
        for (int j = 0; j < 2; ++j) {
            const int g = j * 4 + q;
            f16x8 af[2], bf[4];
#pragma unroll
            for (int t = 0; t < 2; ++t)
                af[t] = *(const f16x8*)(sm + (size_t)(g * 64 + wb0 + t * 16 + li) * 8);
#pragma unroll
            for (int u = 0; u < 4; ++u)
                bf[u] = *(const f16x8*)(sm + (size_t)(512 + g * 128 + ws0 + u * 16 + li) * 8);
#pragma unroll
            for (int t = 0; t < 2; ++t)
#pragma unroll
                for (int u = 0; u < 4; ++u)
                    acc[t][u] = __builtin_amdgcn_mfma_f32_16x16x32_f16(af[t], bf[u], acc[t][u], 0, 0, 0);
        }
    }
#pragma unroll
    for (int t = 0; t < 2; ++t)
#pragma unroll
        for (int u = 0; u < 4; ++u)
#pragma unroll
            for (int r = 0; r < 4; ++r)
                atomicAdd(oacc + (size_t)(bb0 + wb0 + t * 16 + q * 4 + r) * 512 + sb0 + ws0 + u * 16 + li,
                          acc[t][u][r]);
}

// ---------------- finalize ----------------
__global__ void cpsf_fin(const float* __restrict__ oacc, const float* __restrict__ den,
                         float* __restrict__ out)
{
    int i = blockIdx.x * 256 + threadIdx.x;
    float d = (den[i >> 9] + EPS_TOTAL) * WSC;
    out[i] = oacc[i] / d;
}

extern "C" void kernel_launch(void* const* d_in, const int* in_sizes, int n_in,
                              void* d_out, int out_size, void* d_ws, size_t ws_size,
                              hipStream_t stream)
{
    (void)in_sizes; (void)n_in; (void)out_size; (void)ws_size;
    const float* z_re  = (const float*)d_in[0];
    const float* z_im  = (const float*)d_in[1];
    const float* d_re  = (const float*)d_in[2];
    const float* d_im  = (const float*)d_in[3];
    const float* zj_re = (const float*)d_in[4];
    const float* zj_im = (const float*)d_in[5];
    const float* dj_re = (const float*)d_in[6];
    const float* dj_im = (const float*)d_in[7];
    const float* T_re  = (const float*)d_in[8];
    const float* T_im  = (const float*)d_in[9];
    const float* alpha = (const float*)d_in[10];
    const float* s_par = (const float*)d_in[11];
    const float* s_perp= (const float*)d_in[12];

    // workspace layout (bytes); total ~41.1 MB (same footprint as proven R3-R5)
    char* w8 = (char*)d_ws;
    const size_t o_out = 0;
    const size_t o_den = o_out + (size_t)Bq * 512 * 4;   // 2 MB
    const size_t o_z2  = o_den + 4096;
    const size_t o_cm  = o_z2 + 4096;
    const size_t o_az  = o_cm + (size_t)8 * Mm * 4;      // 256 KB
    const size_t o_au  = o_az + (size_t)Bq * 256 * 2;
    const size_t o_bp  = o_au + (size_t)Bq * 256 * 2;
    const size_t o_tt  = o_bp + (size_t)3 * Mm * 256 * 2;   // 12.6 MB
    const size_t o_wb  = o_tt + (size_t)512 * Mm * 2;       // 8.4 MB

    float* oacc = (float*)(w8 + o_out);
    float* den  = (float*)(w8 + o_den);
    float* z2   = (float*)(w8 + o_z2);
    float* cm   = (float*)(w8 + o_cm);
    f16*   Az   = (f16*)(w8 + o_az);
    f16*   Au   = (f16*)(w8 + o_au);
    f16*   Bp   = (f16*)(w8 + o_bp);
    f16*   Tt   = (f16*)(w8 + o_tt);
    f16*   wb   = (f16*)(w8 + o_wb);

    hipMemsetAsync(d_ws, 0, o_cm, stream);   // zero out_acc + den

    cpsf_prep_a<<<Bq / 4, 256, 0, stream>>>(z_re, z_im, d_re, d_im, z2, Az, Au);
    cpsf_prep_m<<<Mm / 4, 256, 0, stream>>>(zj_re, zj_im, dj_re, dj_im,
                                            alpha, s_par, s_perp, cm, Bp);
    cpsf_pack_tt<<<dim3(Mm / 64, Ss / 64), 256, 0, stream>>>(T_re, T_im, Tt);
    cpsf_gemm_w<<<dim3(Mm / 64, Bq / 64), 256, 0, stream>>>(Az, Au, Bp, cm, z2, wb, den);
    cpsf_gemm_out<<<dim3(4, Bq / 64, Mm / 1024), 256, 0, stream>>>(wb, Tt, oacc);
    cpsf_fin<<<(Bq * 512) / 256, 256, 0, stream>>>(oacc, den, (float*)d_out);
}